// Round 1
// baseline (890.843 us; speedup 1.0000x reference)
//
#include <hip/hip_runtime.h>
#include <hip/hip_bf16.h>

#define N_NODES 100000

// ---------------------------------------------------------------------------
// GEMM + optional fused epilogue:
//   out[row][col] = sum_k A[row][k] * W[k][col]
//                 (+ agg[row][col] / max(deg[row],1))  if agg != nullptr
//                 (+ bias[col])                        if bias != nullptr
//                 relu if RELU
// A is [M x 64], W is [64 x NOUT], out is [M x NOUT].
// Block = 256 threads, each thread computes one output element.
// ---------------------------------------------------------------------------
template <int NOUT, bool RELU>
__global__ __launch_bounds__(256) void gemm_k(
    const float* __restrict__ A, const float* __restrict__ W,
    const float* __restrict__ bias, const float* __restrict__ agg,
    const float* __restrict__ deg, float* __restrict__ out, int M) {
  __shared__ float Wl[64 * NOUT];
  const int tid = threadIdx.x;
  for (int i = tid; i < 64 * NOUT; i += 256) Wl[i] = W[i];
  __syncthreads();

  constexpr int ROWS = 256 / NOUT;  // 4 (NOUT=64) or 8 (NOUT=32)
  const int row = blockIdx.x * ROWS + tid / NOUT;
  const int col = tid % NOUT;
  if (row >= M) return;

  const float4* a4 = (const float4*)(A + (long long)row * 64);
  float acc = 0.f;
#pragma unroll
  for (int k4 = 0; k4 < 16; ++k4) {
    float4 av = a4[k4];
    acc = fmaf(av.x, Wl[(4 * k4 + 0) * NOUT + col], acc);
    acc = fmaf(av.y, Wl[(4 * k4 + 1) * NOUT + col], acc);
    acc = fmaf(av.z, Wl[(4 * k4 + 2) * NOUT + col], acc);
    acc = fmaf(av.w, Wl[(4 * k4 + 3) * NOUT + col], acc);
  }
  if (agg) {
    float dv = deg[row];
    dv = dv < 1.f ? 1.f : dv;
    acc += agg[(long long)row * NOUT + col] * (1.f / dv);
  }
  if (bias) acc += bias[col];
  if (RELU) acc = fmaxf(acc, 0.f);
  out[(long long)row * NOUT + col] = acc;
}

// ---------------------------------------------------------------------------
// Scatter-add: for each edge e, agg[dst[e]][:] += val[src[e]][:]
// One thread per (edge, feature). Within a wave, 64 lanes cover one edge's
// 64 features (F=64) or two edges' 32 features (F=32) -> contiguous atomic
// addresses, wave-uniform src/dst loads.
// ---------------------------------------------------------------------------
template <int LOGF, bool COUNT_DEG>
__global__ __launch_bounds__(256) void scatter_k(
    const float* __restrict__ val, const int* __restrict__ src,
    const int* __restrict__ dst, float* __restrict__ agg,
    float* __restrict__ deg, int total) {
  const int idx = blockIdx.x * 256 + threadIdx.x;
  if (idx >= total) return;
  const int e = idx >> LOGF;
  const int f = idx & ((1 << LOGF) - 1);
  const int s = src[e];
  const int d = dst[e];
  atomicAdd(&agg[((long long)d << LOGF) | f], val[((long long)s << LOGF) | f]);
  if (COUNT_DEG && f == 0) atomicAdd(&deg[d], 1.0f);
}

extern "C" void kernel_launch(void* const* d_in, const int* in_sizes, int n_in,
                              void* d_out, int out_size, void* d_ws,
                              size_t ws_size, hipStream_t stream) {
  const float* x    = (const float*)d_in[0];
  const int*   ei   = (const int*)d_in[1];   // [2, E]: row0 = src, row1 = dst
  const float* W1n  = (const float*)d_in[2];
  const float* W1s  = (const float*)d_in[3];
  const float* b1   = (const float*)d_in[4];
  const float* W2n  = (const float*)d_in[5];
  const float* W2s  = (const float*)d_in[6];
  const float* b2   = (const float*)d_in[7];
  float* out = (float*)d_out;

  const int E = in_sizes[1] / 2;  // 1,600,000
  const int M = N_NODES;          // 100,000
  const int* src = ei;
  const int* dst = ei + E;

  // Workspace layout (bytes):
  //   agg : M*64*4 = 25,600,000   (reused as 32-wide agg for layer 2)
  //   buf : M*64*4 = 25,600,000   (xn, reused as hn)
  //   h   : M*64*4 = 25,600,000
  //   deg : M*4    =    400,000
  char* wsb = (char*)d_ws;
  float* agg = (float*)(wsb);
  float* buf = (float*)(wsb + 25600000);
  float* h   = (float*)(wsb + 51200000);
  float* deg = (float*)(wsb + 76800000);

  // ---- Layer 1 ----
  hipMemsetAsync(agg, 0, (size_t)M * 64 * 4, stream);
  hipMemsetAsync(deg, 0, (size_t)M * 4, stream);

  // xn = x @ W1_n
  gemm_k<64, false><<<M / 4, 256, 0, stream>>>(x, W1n, nullptr, nullptr,
                                               nullptr, buf, M);
  // agg[dst] += xn[src]; deg[dst] += 1
  {
    int total = E * 64;
    scatter_k<6, true><<<(total + 255) / 256, 256, 0, stream>>>(
        buf, src, dst, agg, deg, total);
  }
  // h = relu(agg/deg + x @ W1_s + b1)
  gemm_k<64, true><<<M / 4, 256, 0, stream>>>(x, W1s, b1, agg, deg, h, M);

  // ---- Layer 2 ----
  hipMemsetAsync(agg, 0, (size_t)M * 32 * 4, stream);

  // hn = h @ W2_n
  gemm_k<32, false><<<M / 8, 256, 0, stream>>>(h, W2n, nullptr, nullptr,
                                               nullptr, buf, M);
  // agg[dst] += hn[src]
  {
    int total = E * 32;
    scatter_k<5, false><<<(total + 255) / 256, 256, 0, stream>>>(
        buf, src, dst, agg, deg, total);
  }
  // out = agg/deg + h @ W2_s + b2
  gemm_k<32, false><<<M / 8, 256, 0, stream>>>(h, W2s, b2, agg, deg, out, M);
}

// Round 2
// 741.130 us; speedup vs baseline: 1.2020x; 1.2020x over previous
//
#include <hip/hip_runtime.h>
#include <hip/hip_bf16.h>

#define N_NODES 100000
#define NPAD 100352  // 196 * 512, zero-padded for the scan

// ---------------------------------------------------------------------------
// GEMM + fused epilogue. A [M x 64], W [64 x NOUT], out [M x NOUT].
//   out[r][c] = sum_k A[r][k]*W[k][c] (+ agg[r][c]) (+ bias[c]) (relu)
// Each thread computes 4 rows x 1 col: every LDS W read feeds 4 FMAs
// (LDS traffic /4 vs 1-row/thread) and gives 4 independent acc chains.
// ---------------------------------------------------------------------------
template <int NOUT, bool RELU>
__global__ __launch_bounds__(256) void gemm_k(
    const float* __restrict__ A, const float* __restrict__ W,
    const float* __restrict__ bias, const float* __restrict__ agg,
    float* __restrict__ out, int M) {
  __shared__ float Wl[64 * NOUT];
  const int tid = threadIdx.x;
  for (int i = tid; i < 64 * NOUT; i += 256) Wl[i] = W[i];
  __syncthreads();

  constexpr int GROUPS = 256 / NOUT;          // 4 (NOUT=64) or 8 (NOUT=32)
  constexpr int ROWS_PER_BLOCK = GROUPS * 4;  // 16 or 32
  const int col = tid % NOUT;
  const int g = tid / NOUT;
  const long long row0 = (long long)blockIdx.x * ROWS_PER_BLOCK + g * 4;
  if (row0 >= M) return;

  const float4* a0 = (const float4*)(A + (row0 + 0) * 64);
  const float4* a1 = (const float4*)(A + (row0 + 1) * 64);
  const float4* a2 = (const float4*)(A + (row0 + 2) * 64);
  const float4* a3 = (const float4*)(A + (row0 + 3) * 64);
  float c0 = 0.f, c1 = 0.f, c2 = 0.f, c3 = 0.f;
#pragma unroll
  for (int k4 = 0; k4 < 16; ++k4) {
    float4 v0 = a0[k4], v1 = a1[k4], v2 = a2[k4], v3 = a3[k4];
    float w0 = Wl[(4 * k4 + 0) * NOUT + col];
    float w1 = Wl[(4 * k4 + 1) * NOUT + col];
    float w2 = Wl[(4 * k4 + 2) * NOUT + col];
    float w3 = Wl[(4 * k4 + 3) * NOUT + col];
    c0 = fmaf(v0.x, w0, c0); c0 = fmaf(v0.y, w1, c0);
    c0 = fmaf(v0.z, w2, c0); c0 = fmaf(v0.w, w3, c0);
    c1 = fmaf(v1.x, w0, c1); c1 = fmaf(v1.y, w1, c1);
    c1 = fmaf(v1.z, w2, c1); c1 = fmaf(v1.w, w3, c1);
    c2 = fmaf(v2.x, w0, c2); c2 = fmaf(v2.y, w1, c2);
    c2 = fmaf(v2.z, w2, c2); c2 = fmaf(v2.w, w3, c2);
    c3 = fmaf(v3.x, w0, c3); c3 = fmaf(v3.y, w1, c3);
    c3 = fmaf(v3.z, w2, c3); c3 = fmaf(v3.w, w3, c3);
  }
  float b = bias ? bias[col] : 0.f;
  float r[4] = {c0, c1, c2, c3};
#pragma unroll
  for (int i = 0; i < 4; ++i) {
    float v = r[i] + b;
    if (agg) v += agg[(row0 + i) * NOUT + col];
    if (RELU) v = fmaxf(v, 0.f);
    out[(row0 + i) * NOUT + col] = v;
  }
}

// --------------------------- CSR construction ------------------------------
__global__ __launch_bounds__(256) void hist_k(const int* __restrict__ dst,
                                              unsigned* __restrict__ deg, int E) {
  int e = blockIdx.x * 256 + threadIdx.x;
  if (e < E) atomicAdd(&deg[dst[e]], 1u);
}

// Phase A: per-block (chunk=512) sums.
__global__ __launch_bounds__(256) void scanA(const unsigned* __restrict__ deg,
                                             unsigned* __restrict__ bsums) {
  __shared__ unsigned s[256];
  int base = blockIdx.x * 512;
  unsigned v = deg[base + threadIdx.x] + deg[base + 256 + threadIdx.x];
  s[threadIdx.x] = v;
  __syncthreads();
  for (int off = 128; off; off >>= 1) {
    if (threadIdx.x < off) s[threadIdx.x] += s[threadIdx.x + off];
    __syncthreads();
  }
  if (threadIdx.x == 0) bsums[blockIdx.x] = s[0];
}

// Phase B: exclusive scan of the (<=256) block sums, single block.
__global__ __launch_bounds__(256) void scanB(const unsigned* __restrict__ bsums,
                                             unsigned* __restrict__ bex, int nb) {
  __shared__ unsigned s[256];
  int tid = threadIdx.x;
  unsigned v = (tid < nb) ? bsums[tid] : 0u;
  s[tid] = v;
  __syncthreads();
  for (int off = 1; off < 256; off <<= 1) {
    unsigned t = (tid >= off) ? s[tid - off] : 0u;
    __syncthreads();
    s[tid] += t;
    __syncthreads();
  }
  if (tid < nb) bex[tid] = s[tid] - v;  // exclusive
}

// Phase C: per-chunk exclusive scan + block offset -> row_start & cursor.
__global__ __launch_bounds__(512) void scanC(const unsigned* __restrict__ deg,
                                             const unsigned* __restrict__ bex,
                                             unsigned* __restrict__ row_start,
                                             unsigned* __restrict__ cursor) {
  __shared__ unsigned s[512];
  int tid = threadIdx.x;
  int i = blockIdx.x * 512 + tid;
  unsigned v = deg[i];
  s[tid] = v;
  __syncthreads();
  for (int off = 1; off < 512; off <<= 1) {
    unsigned t = (tid >= off) ? s[tid - off] : 0u;
    __syncthreads();
    s[tid] += t;
    __syncthreads();
  }
  unsigned ex = bex[blockIdx.x] + s[tid] - v;
  row_start[i] = ex;
  cursor[i] = ex;
}

__global__ __launch_bounds__(256) void reorder_k(const int* __restrict__ src,
                                                 const int* __restrict__ dst,
                                                 unsigned* __restrict__ cursor,
                                                 int* __restrict__ ssrc, int E) {
  int e = blockIdx.x * 256 + threadIdx.x;
  if (e < E) {
    unsigned p = atomicAdd(&cursor[dst[e]], 1u);
    ssrc[p] = src[e];
  }
}

// ---------------------------------------------------------------------------
// Gather-aggregate (mean): out[node][:] = (1/deg) * sum_{j in CSR(node)} val[ssrc[j]][:]
// F lanes per node (F=64 or 32), features coalesced across lanes; no atomics.
// ---------------------------------------------------------------------------
template <int LOGF>
__global__ __launch_bounds__(256) void gather_k(
    const float* __restrict__ val, const int* __restrict__ ssrc,
    const unsigned* __restrict__ row_start, float* __restrict__ out, int N) {
  constexpr int F = 1 << LOGF;
  const int node = blockIdx.x * (256 >> LOGF) + (threadIdx.x >> LOGF);
  const int f = threadIdx.x & (F - 1);
  if (node >= N) return;
  const unsigned beg = row_start[node], end = row_start[node + 1];
  float acc = 0.f;
  unsigned j = beg;
  for (; j + 2 <= end; j += 2) {
    int s0 = ssrc[j], s1 = ssrc[j + 1];
    float a = val[((long long)s0 << LOGF) | f];
    float b = val[((long long)s1 << LOGF) | f];
    acc += a + b;
  }
  if (j < end) acc += val[((long long)ssrc[j] << LOGF) | f];
  const unsigned d = end - beg;
  const float inv = d ? 1.f / (float)d : 0.f;  // deg=0 -> mean=0 (matches ref)
  out[((long long)node << LOGF) | f] = acc * inv;
}

extern "C" void kernel_launch(void* const* d_in, const int* in_sizes, int n_in,
                              void* d_out, int out_size, void* d_ws,
                              size_t ws_size, hipStream_t stream) {
  const float* x   = (const float*)d_in[0];
  const int*   ei  = (const int*)d_in[1];  // [2, E]: row0 = src, row1 = dst
  const float* W1n = (const float*)d_in[2];
  const float* W1s = (const float*)d_in[3];
  const float* b1  = (const float*)d_in[4];
  const float* W2n = (const float*)d_in[5];
  const float* W2s = (const float*)d_in[6];
  const float* b2  = (const float*)d_in[7];
  float* out = (float*)d_out;

  const int E = in_sizes[1] / 2;  // 1,600,000
  const int M = N_NODES;
  const int* src = ei;
  const int* dst = ei + E;

  // Workspace layout (bytes):
  //   buf        @ 0          25,600,000  (xn; layer2: hn [12.8MB] + agg2 [12.8MB])
  //   h          @ 25,600,000 25,600,000  (mean1 in-place -> h)
  //   sorted_src @ 51,200,000  6,400,000
  //   deg_i      @ 57,600,000    401,408  (NPAD u32)
  //   row_start  @ 58,001,408    401,408
  //   cursor     @ 58,402,816    401,408
  //   bsums      @ 58,804,224      1,024
  //   bex        @ 58,805,248      1,024
  char* wsb = (char*)d_ws;
  float*    buf  = (float*)(wsb);
  float*    h    = (float*)(wsb + 25600000);
  int*      ssrc = (int*)(wsb + 51200000);
  unsigned* degi = (unsigned*)(wsb + 57600000);
  unsigned* rows = (unsigned*)(wsb + 58001408);
  unsigned* curs = (unsigned*)(wsb + 58402816);
  unsigned* bsum = (unsigned*)(wsb + 58804224);
  unsigned* bex  = (unsigned*)(wsb + 58805248);

  float* hn   = buf;            // layer-2: [M x 32]
  float* agg2 = buf + 3200000;  // layer-2 mean: [M x 32]

  // ---- CSR by dst (shared by both layers) ----
  hipMemsetAsync(degi, 0, (size_t)NPAD * 4, stream);
  hist_k<<<E / 256, 256, 0, stream>>>(dst, degi, E);
  scanA<<<NPAD / 512, 256, 0, stream>>>(degi, bsum);
  scanB<<<1, 256, 0, stream>>>(bsum, bex, NPAD / 512);
  scanC<<<NPAD / 512, 512, 0, stream>>>(degi, bex, rows, curs);
  reorder_k<<<E / 256, 256, 0, stream>>>(src, dst, curs, ssrc, E);

  // ---- Layer 1 ----
  gemm_k<64, false><<<(M + 15) / 16, 256, 0, stream>>>(x, W1n, nullptr, nullptr,
                                                       buf, M);
  gather_k<6><<<M / 4, 256, 0, stream>>>(buf, ssrc, rows, h, M);  // mean1 -> h
  // h = relu(mean1 + x@W1_s + b1), in-place over mean1
  gemm_k<64, true><<<(M + 15) / 16, 256, 0, stream>>>(x, W1s, b1, h, h, M);

  // ---- Layer 2 ----
  gemm_k<32, false><<<(M + 31) / 32, 256, 0, stream>>>(h, W2n, nullptr, nullptr,
                                                       hn, M);
  gather_k<5><<<M / 8, 256, 0, stream>>>(hn, ssrc, rows, agg2, M);  // mean2
  gemm_k<32, false><<<(M + 31) / 32, 256, 0, stream>>>(h, W2s, b2, agg2, out, M);
}

// Round 3
// 520.191 us; speedup vs baseline: 1.7125x; 1.4247x over previous
//
#include <hip/hip_runtime.h>
#include <hip/hip_bf16.h>

#define N_NODES 100000
#define NPAD 100352  // 196 * 512, zero-padded for the scan

// ---------------------------------------------------------------------------
// Fused dual-GEMM, layer 1:
//   h[r][c] = relu( sum_k mean1[r][k]*W1n[k][c] + sum_k x[r][k]*W1s[k][c] + b1[c] )
// A-matrices differ (mean1, x), both [M x 64]; NOUT=64.
// Each thread: 4 rows x 1 col for both GEMMs (LDS W reads amortized 4x).
// ---------------------------------------------------------------------------
__global__ __launch_bounds__(256) void gemm1_k(
    const float* __restrict__ mean1, const float* __restrict__ x,
    const float* __restrict__ W1n, const float* __restrict__ W1s,
    const float* __restrict__ b1, float* __restrict__ h, int M) {
  __shared__ float Wn[64 * 64];
  __shared__ float Ws[64 * 64];
  const int tid = threadIdx.x;
  for (int i = tid; i < 64 * 64; i += 256) {
    Wn[i] = W1n[i];
    Ws[i] = W1s[i];
  }
  __syncthreads();

  const int col = tid & 63;
  const int g = tid >> 6;  // 0..3
  const long long row0 = (long long)blockIdx.x * 16 + g * 4;
  if (row0 >= M) return;

  float acc[4] = {0.f, 0.f, 0.f, 0.f};
#pragma unroll
  for (int k4 = 0; k4 < 16; ++k4) {
#pragma unroll
    for (int r = 0; r < 4; ++r) {
      float4 mv = ((const float4*)(mean1 + (row0 + r) * 64))[k4];
      float4 xv = ((const float4*)(x + (row0 + r) * 64))[k4];
      acc[r] = fmaf(mv.x, Wn[(4 * k4 + 0) * 64 + col], acc[r]);
      acc[r] = fmaf(mv.y, Wn[(4 * k4 + 1) * 64 + col], acc[r]);
      acc[r] = fmaf(mv.z, Wn[(4 * k4 + 2) * 64 + col], acc[r]);
      acc[r] = fmaf(mv.w, Wn[(4 * k4 + 3) * 64 + col], acc[r]);
      acc[r] = fmaf(xv.x, Ws[(4 * k4 + 0) * 64 + col], acc[r]);
      acc[r] = fmaf(xv.y, Ws[(4 * k4 + 1) * 64 + col], acc[r]);
      acc[r] = fmaf(xv.z, Ws[(4 * k4 + 2) * 64 + col], acc[r]);
      acc[r] = fmaf(xv.w, Ws[(4 * k4 + 3) * 64 + col], acc[r]);
    }
  }
  const float b = b1[col];
#pragma unroll
  for (int r = 0; r < 4; ++r)
    h[(row0 + r) * 64 + col] = fmaxf(acc[r] + b, 0.f);
}

// ---------------------------------------------------------------------------
// Fused dual-GEMM, layer 2: one pass over h produces
//   hn[r][c] = sum_k h[r][k]*W2n[k][c]
//   hs[r][c] = sum_k h[r][k]*W2s[k][c] + b2[c]
// A shared between both outputs. NOUT=32; thread: 4 rows x 1 col x 2 outs.
// ---------------------------------------------------------------------------
__global__ __launch_bounds__(256) void gemm2_k(
    const float* __restrict__ h, const float* __restrict__ W2n,
    const float* __restrict__ W2s, const float* __restrict__ b2,
    float* __restrict__ hn, float* __restrict__ hs, int M) {
  __shared__ float Wn[64 * 32];
  __shared__ float Ws[64 * 32];
  const int tid = threadIdx.x;
  for (int i = tid; i < 64 * 32; i += 256) {
    Wn[i] = W2n[i];
    Ws[i] = W2s[i];
  }
  __syncthreads();

  const int col = tid & 31;
  const int g = tid >> 5;  // 0..7
  const long long row0 = (long long)blockIdx.x * 32 + g * 4;
  if (row0 >= M) return;

  float an[4] = {0.f, 0.f, 0.f, 0.f};
  float as[4] = {0.f, 0.f, 0.f, 0.f};
#pragma unroll
  for (int k4 = 0; k4 < 16; ++k4) {
#pragma unroll
    for (int r = 0; r < 4; ++r) {
      float4 v = ((const float4*)(h + (row0 + r) * 64))[k4];
      an[r] = fmaf(v.x, Wn[(4 * k4 + 0) * 32 + col], an[r]);
      an[r] = fmaf(v.y, Wn[(4 * k4 + 1) * 32 + col], an[r]);
      an[r] = fmaf(v.z, Wn[(4 * k4 + 2) * 32 + col], an[r]);
      an[r] = fmaf(v.w, Wn[(4 * k4 + 3) * 32 + col], an[r]);
      as[r] = fmaf(v.x, Ws[(4 * k4 + 0) * 32 + col], as[r]);
      as[r] = fmaf(v.y, Ws[(4 * k4 + 1) * 32 + col], as[r]);
      as[r] = fmaf(v.z, Ws[(4 * k4 + 2) * 32 + col], as[r]);
      as[r] = fmaf(v.w, Ws[(4 * k4 + 3) * 32 + col], as[r]);
    }
  }
  const float b = b2[col];
#pragma unroll
  for (int r = 0; r < 4; ++r) {
    hn[(row0 + r) * 32 + col] = an[r];
    hs[(row0 + r) * 32 + col] = as[r] + b;
  }
}

// --------------------------- CSR construction ------------------------------
__global__ __launch_bounds__(256) void hist_k(const int* __restrict__ dst,
                                              unsigned* __restrict__ deg, int E) {
  int e = blockIdx.x * 256 + threadIdx.x;
  if (e < E) atomicAdd(&deg[dst[e]], 1u);
}

__global__ __launch_bounds__(256) void scanA(const unsigned* __restrict__ deg,
                                             unsigned* __restrict__ bsums) {
  __shared__ unsigned s[256];
  int base = blockIdx.x * 512;
  unsigned v = deg[base + threadIdx.x] + deg[base + 256 + threadIdx.x];
  s[threadIdx.x] = v;
  __syncthreads();
  for (int off = 128; off; off >>= 1) {
    if (threadIdx.x < off) s[threadIdx.x] += s[threadIdx.x + off];
    __syncthreads();
  }
  if (threadIdx.x == 0) bsums[blockIdx.x] = s[0];
}

__global__ __launch_bounds__(256) void scanB(const unsigned* __restrict__ bsums,
                                             unsigned* __restrict__ bex, int nb) {
  __shared__ unsigned s[256];
  int tid = threadIdx.x;
  unsigned v = (tid < nb) ? bsums[tid] : 0u;
  s[tid] = v;
  __syncthreads();
  for (int off = 1; off < 256; off <<= 1) {
    unsigned t = (tid >= off) ? s[tid - off] : 0u;
    __syncthreads();
    s[tid] += t;
    __syncthreads();
  }
  if (tid < nb) bex[tid] = s[tid] - v;  // exclusive
}

__global__ __launch_bounds__(512) void scanC(const unsigned* __restrict__ deg,
                                             const unsigned* __restrict__ bex,
                                             unsigned* __restrict__ row_start,
                                             unsigned* __restrict__ cursor) {
  __shared__ unsigned s[512];
  int tid = threadIdx.x;
  int i = blockIdx.x * 512 + tid;
  unsigned v = deg[i];
  s[tid] = v;
  __syncthreads();
  for (int off = 1; off < 512; off <<= 1) {
    unsigned t = (tid >= off) ? s[tid - off] : 0u;
    __syncthreads();
    s[tid] += t;
    __syncthreads();
  }
  unsigned ex = bex[blockIdx.x] + s[tid] - v;
  row_start[i] = ex;
  cursor[i] = ex;
}

__global__ __launch_bounds__(256) void reorder_k(const int* __restrict__ src,
                                                 const int* __restrict__ dst,
                                                 unsigned* __restrict__ cursor,
                                                 int* __restrict__ ssrc, int E) {
  int e = blockIdx.x * 256 + threadIdx.x;
  if (e < E) {
    unsigned p = atomicAdd(&cursor[dst[e]], 1u);
    ssrc[p] = src[e];
  }
}

// ---------------------------------------------------------------------------
// Gather-mean, unroll-4 for memory ILP (deg~16, L3-latency-bound):
//   out[node][f] = base_term + (1/deg) * sum_j val[ssrc[j]][f]
// If ADD_BASE: base read sequentially from `base` (layer-2 fusion of hs).
// ---------------------------------------------------------------------------
template <int LOGF, bool ADD_BASE>
__global__ __launch_bounds__(256) void gather_k(
    const float* __restrict__ val, const int* __restrict__ ssrc,
    const unsigned* __restrict__ row_start, const float* __restrict__ base,
    float* __restrict__ out, int N) {
  constexpr int F = 1 << LOGF;
  const int node = blockIdx.x * (256 >> LOGF) + (threadIdx.x >> LOGF);
  const int f = threadIdx.x & (F - 1);
  if (node >= N) return;
  const unsigned beg = row_start[node], end = row_start[node + 1];
  float acc = 0.f;
  unsigned j = beg;
  for (; j + 4 <= end; j += 4) {
    int s0 = ssrc[j], s1 = ssrc[j + 1], s2 = ssrc[j + 2], s3 = ssrc[j + 3];
    float a = val[((long long)s0 << LOGF) | f];
    float b = val[((long long)s1 << LOGF) | f];
    float c = val[((long long)s2 << LOGF) | f];
    float d = val[((long long)s3 << LOGF) | f];
    acc += (a + b) + (c + d);
  }
  for (; j < end; ++j) acc += val[((long long)ssrc[j] << LOGF) | f];
  const unsigned dg = end - beg;
  const float inv = dg ? 1.f / (float)dg : 0.f;
  float v = acc * inv;
  if (ADD_BASE) v += base[((long long)node << LOGF) | f];
  out[((long long)node << LOGF) | f] = v;
}

extern "C" void kernel_launch(void* const* d_in, const int* in_sizes, int n_in,
                              void* d_out, int out_size, void* d_ws,
                              size_t ws_size, hipStream_t stream) {
  const float* x   = (const float*)d_in[0];
  const int*   ei  = (const int*)d_in[1];  // [2, E]: row0 = src, row1 = dst
  const float* W1n = (const float*)d_in[2];
  const float* W1s = (const float*)d_in[3];
  const float* b1  = (const float*)d_in[4];
  const float* W2n = (const float*)d_in[5];
  const float* W2s = (const float*)d_in[6];
  const float* b2  = (const float*)d_in[7];
  float* out = (float*)d_out;

  const int E = in_sizes[1] / 2;  // 1,600,000
  const int M = N_NODES;
  const int* src = ei;
  const int* dst = ei + E;

  // Workspace layout (bytes):
  //   region0    @ 0          25,600,000  (mean1 [Mx64]; layer2: hn [Mx32] @0 + hs [Mx32] @12.8M)
  //   h          @ 25,600,000 25,600,000
  //   sorted_src @ 51,200,000  6,400,000
  //   deg_i      @ 57,600,000    401,408  (NPAD u32)
  //   row_start  @ 58,001,408    401,408
  //   cursor     @ 58,402,816    401,408
  //   bsums      @ 58,804,224      1,024
  //   bex        @ 58,805,248      1,024
  char* wsb = (char*)d_ws;
  float*    mean1 = (float*)(wsb);
  float*    h     = (float*)(wsb + 25600000);
  int*      ssrc  = (int*)(wsb + 51200000);
  unsigned* degi  = (unsigned*)(wsb + 57600000);
  unsigned* rows  = (unsigned*)(wsb + 58001408);
  unsigned* curs  = (unsigned*)(wsb + 58402816);
  unsigned* bsum  = (unsigned*)(wsb + 58804224);
  unsigned* bex   = (unsigned*)(wsb + 58805248);

  float* hn = (float*)(wsb);             // layer-2: [M x 32]
  float* hs = (float*)(wsb + 12800000);  // layer-2: [M x 32]

  // ---- CSR by dst (shared by both layers) ----
  hipMemsetAsync(degi, 0, (size_t)NPAD * 4, stream);
  hist_k<<<E / 256, 256, 0, stream>>>(dst, degi, E);
  scanA<<<NPAD / 512, 256, 0, stream>>>(degi, bsum);
  scanB<<<1, 256, 0, stream>>>(bsum, bex, NPAD / 512);
  scanC<<<NPAD / 512, 512, 0, stream>>>(degi, bex, rows, curs);
  reorder_k<<<E / 256, 256, 0, stream>>>(src, dst, curs, ssrc, E);

  // ---- Layer 1 (gather-first: mean1 = mean(x[src]); h fused dual-GEMM) ----
  gather_k<6, false><<<M / 4, 256, 0, stream>>>(x, ssrc, rows, nullptr, mean1, M);
  gemm1_k<<<(M + 15) / 16, 256, 0, stream>>>(mean1, x, W1n, W1s, b1, h, M);

  // ---- Layer 2 (gemm-first: hn/hs in one pass; out fused into gather) ----
  gemm2_k<<<(M + 31) / 32, 256, 0, stream>>>(h, W2n, W2s, b2, hn, hs, M);
  gather_k<5, true><<<M / 8, 256, 0, stream>>>(hn, ssrc, rows, hs, out, M);
}